// Round 11
// baseline (309.469 us; speedup 1.0000x reference)
//
#include <hip/hip_runtime.h>

#define IN_SIZE 128
#define HID 256
#define N_SRC1 500000
#define N_DST1 100000
#define E1 1600000
#define N_DST2 16384
#define E2 262144

// radix fill: bins of 512 dst, atomic-free (hist -> offsets -> place -> sort)
#define NBIN1 196          // ceil(100000/512)
#define NBIN2 32           // 16384/512
#define P1B1  800          // layer-1 blocks, chunk = E1/800 = 2000 edges
#define P1B2  256          // layer-2 blocks, chunk = E2/256 = 1024 edges

// k_main1 block roles: [0,1056) hist, [1056,1152) pack, [1152,3456) cast
#define MB_HIST (P1B1 + P1B2)       // 1056
#define MB_PACK 96
#define MB_CAST 2304
#define MB_TOTAL (MB_HIST + MB_PACK + MB_CAST)   // 3456

// ---------------- workspace layout (bytes), total 221,220,224 ----------------
// ws_size ~= 1.02 GB (harness poison), no aliasing anywhere.
#define OFF_XBF  0ull           // xbf [500000][128] bf16 (128,000,000)
#define OFF_H    128000000ull   // h [100000][256] bf16   (51,200,000)
#define OFF_MSG1 179200000ull   // msg1 [100000][128] bf16 (25,600,000)
#define OFF_STG1 204800000ull   // staging1 [1.6M] u32    (6,400,000)
#define OFF_STG2 211200000ull   // staging2 [262144] u32  (1,048,576)
#define OFF_BP1  212248576ull   // hist/blkpref1 [800][196] i32 (627,200)
#define OFF_BP2  212875776ull   // hist/blkpref2 [256][32] i32  (32,768)
#define OFF_BT1  212908544ull   // bin totals1 (1,024)
#define OFF_BT2  212909568ull   // bin totals2 (1,024)
#define OFF_RP1  212912640ull   // rowptr1 [100001] i32 (400,128)
#define OFF_RP2  213312768ull   // rowptr2 [16385] i32  (65,664)
#define OFF_CSR1 213378432ull   // csr1 [1,600,000] i32 (6,400,000)
#define OFF_CSR2 219778432ull   // csr2 [262,144] i32   (1,048,576)
#define OFF_WP1  220827008ull   // packed W1 bf16 (131,072)
#define OFF_WP2  220958080ull   // packed W2 bf16 (262,144)

typedef __attribute__((ext_vector_type(8))) short short8;
typedef __attribute__((ext_vector_type(4))) float f32x4;

__device__ __forceinline__ unsigned short f2bf(float f) {
    unsigned u = __float_as_uint(f);
    return (unsigned short)((u + 0x7FFFu + ((u >> 16) & 1u)) >> 16);
}
__device__ __forceinline__ float bf2f(unsigned short b) {
    return __uint_as_float(((unsigned)b) << 16);
}

// ---------------- fused: bin-histograms | weight-pack | streaming cast ----------------
__global__ __launch_bounds__(256) void k_main1(
    const float* __restrict__ x, unsigned short* __restrict__ xbf,
    const int* __restrict__ dst1, int* __restrict__ hist1,
    const int* __restrict__ dst2, int* __restrict__ hist2,
    const float* __restrict__ Ws1, const float* __restrict__ Wn1,
    unsigned short* __restrict__ wp1,
    const float* __restrict__ Ws2, const float* __restrict__ Wn2,
    unsigned short* __restrict__ wp2)
{
    __shared__ int lcnt[NBIN1];
    const int bid = blockIdx.x;
    const int tid = threadIdx.x;

    if (bid < MB_HIST) {
        // ---- histogram-only blocks ----
        const bool l1 = bid < P1B1;
        const int blk = l1 ? bid : bid - P1B1;
        const int nbins = l1 ? NBIN1 : NBIN2;
        const int chunk = l1 ? (E1 / P1B1) : (E2 / P1B2);
        const int* dst = l1 ? dst1 : dst2;
        int* hist = l1 ? hist1 : hist2;
        const int e0 = blk * chunk;
        for (int i = tid; i < nbins; i += 256) lcnt[i] = 0;
        __syncthreads();
        for (int i = tid; i < chunk; i += 256)
            atomicAdd(&lcnt[dst[e0 + i] >> 9], 1);
        __syncthreads();
        for (int i = tid; i < nbins; i += 256)
            hist[blk * nbins + i] = lcnt[i];     // coalesced
    } else if (bid < MB_HIST + MB_PACK) {
        // ---- weight-pack blocks ----
        const int pb = bid - MB_HIST;
        const bool l1 = pb < 32;
        const int Keach = l1 ? 128 : 256;
        const float* Wa = l1 ? Ws1 : Ws2;
        const float* Wb = l1 ? Wn1 : Wn2;
        unsigned short* outp = l1 ? wp1 : wp2;
        const int t = (l1 ? pb : pb - 32) * 256 + tid;
        const int kb = t >> 10;
        const int c  = (t >> 2) & 255;
        const int g  = t & 3;
        const int kbase = kb * 32 + g * 8;
        const float* W = (kbase < Keach) ? (Wa + (size_t)kbase * HID + c)
                                         : (Wb + (size_t)(kbase - Keach) * HID + c);
        unsigned short* o = outp + ((size_t)kb * 256 + c) * 32 + g * 8;
        #pragma unroll
        for (int j = 0; j < 8; ++j) o[j] = f2bf(W[(size_t)j * HID]);
    } else {
        // ---- cast-only blocks ----
        const int cb = bid - MB_HIST - MB_PACK;
        const int T = MB_CAST * 256;
        const float4* x4 = (const float4*)x;
        short8* o8 = (short8*)xbf;
        for (int i = cb * 256 + tid; i < N_SRC1 * IN_SIZE / 8; i += T) {
            const float4 u0 = x4[(size_t)i * 2];
            const float4 u1 = x4[(size_t)i * 2 + 1];
            short8 o;
            o[0] = (short)f2bf(u0.x); o[1] = (short)f2bf(u0.y);
            o[2] = (short)f2bf(u0.z); o[3] = (short)f2bf(u0.w);
            o[4] = (short)f2bf(u1.x); o[5] = (short)f2bf(u1.y);
            o[6] = (short)f2bf(u1.z); o[7] = (short)f2bf(u1.w);
            o8[i] = o;
        }
    }
}

// ---------------- radix B: per-bin block-prefix + bin totals ----------------
// In-place safe: each bin column read fully into registers before rewrite.
__global__ __launch_bounds__(256) void k_scan_offs(
    const int* __restrict__ hist1, int* __restrict__ blkpref1, int* __restrict__ bintot1,
    const int* __restrict__ hist2, int* __restrict__ blkpref2, int* __restrict__ bintot2)
{
    __shared__ int s[256];
    const int tid = threadIdx.x;
    const bool l1 = blockIdx.x < NBIN1;
    const int b = l1 ? blockIdx.x : blockIdx.x - NBIN1;
    const int nblk = l1 ? P1B1 : P1B2;
    const int nbins = l1 ? NBIN1 : NBIN2;
    const int* hist = l1 ? hist1 : hist2;
    int* blkpref = l1 ? blkpref1 : blkpref2;
    int* bintot = l1 ? bintot1 : bintot2;

    int v[4];
    int lsum = 0;
    #pragma unroll
    for (int j = 0; j < 4; ++j) {
        const int idx = tid * 4 + j;
        v[j] = (idx < nblk) ? hist[idx * nbins + b] : 0;
        lsum += v[j];
    }
    s[tid] = lsum;
    __syncthreads();
    for (int off = 1; off < 256; off <<= 1) {
        int t = (tid >= off) ? s[tid - off] : 0;
        __syncthreads();
        s[tid] += t;
        __syncthreads();
    }
    int run = s[tid] - lsum;
    #pragma unroll
    for (int j = 0; j < 4; ++j) {
        const int idx = tid * 4 + j;
        if (idx < nblk) blkpref[idx * nbins + b] = run;
        run += v[j];
    }
    if (tid == 255) bintot[b] = s[255];
}

// ---------------- radix C: place packed entries at precomputed slots ----------------
// Bin-level rowptr recomputed in-block from bintot (196-entry LDS scan).
__global__ __launch_bounds__(256) void k_place(
    const int* __restrict__ src1, const int* __restrict__ dst1,
    const int* __restrict__ blkpref1, const int* __restrict__ bintot1,
    unsigned* __restrict__ stg1,
    const int* __restrict__ src2, const int* __restrict__ dst2,
    const int* __restrict__ blkpref2, const int* __restrict__ bintot2,
    unsigned* __restrict__ stg2)
{
    __shared__ int lcur[NBIN1];
    __shared__ int sp[256];
    const int tid = threadIdx.x;
    const bool l1 = blockIdx.x < P1B1;
    const int blk = l1 ? blockIdx.x : blockIdx.x - P1B1;
    const int nbins = l1 ? NBIN1 : NBIN2;
    const int chunk = l1 ? (E1 / P1B1) : (E2 / P1B2);
    const int* src = l1 ? src1 : src2;
    const int* dst = l1 ? dst1 : dst2;
    const int* blkpref = l1 ? blkpref1 : blkpref2;
    const int* bintot = l1 ? bintot1 : bintot2;
    unsigned* stg = l1 ? stg1 : stg2;
    const int e0 = blk * chunk;

    // exclusive prefix of bintot -> bin rowptr, fused with blkpref add
    const int bv = (tid < nbins) ? bintot[tid] : 0;
    sp[tid] = bv;
    __syncthreads();
    for (int off = 1; off < 256; off <<= 1) {
        int t = (tid >= off) ? sp[tid - off] : 0;
        __syncthreads();
        sp[tid] += t;
        __syncthreads();
    }
    if (tid < nbins) lcur[tid] = (sp[tid] - bv) + blkpref[blk * nbins + tid];
    __syncthreads();

    for (int i = tid; i < chunk; i += 256) {
        const int e = e0 + i;
        const int d = dst[e];
        const unsigned pk = ((unsigned)(d & 511) << 19) | (unsigned)src[e];
        const int pos = atomicAdd(&lcur[d >> 9], 1);
        stg[pos] = pk;
    }
}

// ---------------- radix D: per-bin hist -> scan -> rowptr -> counting sort ----------------
// Bin-level rowptr recomputed in-block from bintot.
__global__ __launch_bounds__(512) void k_fill_p2b(
    const unsigned* __restrict__ stg1, const int* __restrict__ bintot1,
    int* __restrict__ rp1, int* __restrict__ csr1,
    const unsigned* __restrict__ stg2, const int* __restrict__ bintot2,
    int* __restrict__ rp2, int* __restrict__ csr2)
{
    __shared__ int lcnt[512];
    __shared__ int s[512];
    __shared__ int rbv[2];
    const int tid = threadIdx.x;
    const bool l1 = blockIdx.x < NBIN1;
    const int b = l1 ? blockIdx.x : blockIdx.x - NBIN1;
    const int base = b << 9;
    const int ndst = l1 ? N_DST1 : N_DST2;
    const int nbins = l1 ? NBIN1 : NBIN2;
    const int nr = min(512, ndst - base);
    const unsigned* stg = l1 ? stg1 : stg2;
    const int* bintot = l1 ? bintot1 : bintot2;
    int* rp = l1 ? rp1 : rp2;
    int* csr = l1 ? csr1 : csr2;

    // bin rowptr: s0 = excl prefix at b, s1 = incl prefix at b
    const int bv = (tid < nbins) ? bintot[tid] : 0;
    s[tid] = bv;
    __syncthreads();
    for (int off = 1; off < 512; off <<= 1) {
        int t = (tid >= off) ? s[tid - off] : 0;
        __syncthreads();
        s[tid] += t;
        __syncthreads();
    }
    if (tid == b) { rbv[0] = s[tid] - bv; rbv[1] = s[tid]; }
    __syncthreads();
    const int s0 = rbv[0], s1 = rbv[1];

    lcnt[tid] = 0;
    __syncthreads();
    for (int i = s0 + tid; i < s1; i += 512)
        atomicAdd(&lcnt[stg[i] >> 19], 1);
    __syncthreads();

    const int v = lcnt[tid];
    s[tid] = v;
    __syncthreads();
    for (int off = 1; off < 512; off <<= 1) {
        int t = (tid >= off) ? s[tid - off] : 0;
        __syncthreads();
        s[tid] += t;
        __syncthreads();
    }
    const int excl = s0 + s[tid] - v;
    if (tid < nr) rp[base + tid] = excl;
    if (base + tid == ndst - 1) rp[ndst] = s1;
    __syncthreads();
    lcnt[tid] = excl;          // reuse as cursor
    __syncthreads();

    for (int i = s0 + tid; i < s1; i += 512) {
        const unsigned pk = stg[i];
        const int pos = atomicAdd(&lcnt[pk >> 19], 1);
        csr[pos] = (int)(pk & 0x7FFFFu);
    }
}

// ---------------- layer-1 pull (half-wave per dst, 8 edges in flight) ----------------
__global__ __launch_bounds__(256) void k_pull1(
    const unsigned short* __restrict__ xbf, const int* __restrict__ rp,
    const int* __restrict__ csr, unsigned short* __restrict__ msg)
{
    const int d = blockIdx.x * 8 + (threadIdx.x >> 5);
    const int hl = threadIdx.x & 31;
    const int beg = rp[d], end = rp[d + 1];
    float a0 = 0.f, a1 = 0.f, a2 = 0.f, a3 = 0.f;
    const unsigned short* xb = xbf + hl * 4;
    int j = beg;
    for (; j + 7 < end; j += 8) {
        const uint2 v0 = *(const uint2*)(xb + (size_t)csr[j + 0] * IN_SIZE);
        const uint2 v1 = *(const uint2*)(xb + (size_t)csr[j + 1] * IN_SIZE);
        const uint2 v2 = *(const uint2*)(xb + (size_t)csr[j + 2] * IN_SIZE);
        const uint2 v3 = *(const uint2*)(xb + (size_t)csr[j + 3] * IN_SIZE);
        const uint2 v4 = *(const uint2*)(xb + (size_t)csr[j + 4] * IN_SIZE);
        const uint2 v5 = *(const uint2*)(xb + (size_t)csr[j + 5] * IN_SIZE);
        const uint2 v6 = *(const uint2*)(xb + (size_t)csr[j + 6] * IN_SIZE);
        const uint2 v7 = *(const uint2*)(xb + (size_t)csr[j + 7] * IN_SIZE);
        a0 += ((bf2f(v0.x) + bf2f(v1.x)) + (bf2f(v2.x) + bf2f(v3.x)))
            + ((bf2f(v4.x) + bf2f(v5.x)) + (bf2f(v6.x) + bf2f(v7.x)));
        a1 += ((bf2f(v0.x >> 16) + bf2f(v1.x >> 16)) + (bf2f(v2.x >> 16) + bf2f(v3.x >> 16)))
            + ((bf2f(v4.x >> 16) + bf2f(v5.x >> 16)) + (bf2f(v6.x >> 16) + bf2f(v7.x >> 16)));
        a2 += ((bf2f(v0.y) + bf2f(v1.y)) + (bf2f(v2.y) + bf2f(v3.y)))
            + ((bf2f(v4.y) + bf2f(v5.y)) + (bf2f(v6.y) + bf2f(v7.y)));
        a3 += ((bf2f(v0.y >> 16) + bf2f(v1.y >> 16)) + (bf2f(v2.y >> 16) + bf2f(v3.y >> 16)))
            + ((bf2f(v4.y >> 16) + bf2f(v5.y >> 16)) + (bf2f(v6.y >> 16) + bf2f(v7.y >> 16)));
    }
    for (; j < end; ++j) {
        const uint2 va = *(const uint2*)(xb + (size_t)csr[j] * IN_SIZE);
        a0 += bf2f(va.x); a1 += bf2f(va.x >> 16);
        a2 += bf2f(va.y); a3 += bf2f(va.y >> 16);
    }
    const float inv = 1.0f / fmaxf((float)(end - beg), 1.0f);
    uint2 o;
    o.x = (unsigned)f2bf(a0 * inv) | ((unsigned)f2bf(a1 * inv) << 16);
    o.y = (unsigned)f2bf(a2 * inv) | ((unsigned)f2bf(a3 * inv) << 16);
    *(uint2*)(msg + (size_t)d * IN_SIZE + hl * 4) = o;
}

// ---------------- layer-1 MFMA GEMM ----------------
__global__ __launch_bounds__(256) void k_gemm1(
    const unsigned short* __restrict__ A1,  // xbf [M][128]
    const unsigned short* __restrict__ A2,  // msg1 [M][128]
    const unsigned short* __restrict__ Wp,
    const float* __restrict__ bias,
    unsigned short* __restrict__ out)       // h bf16 [M][256]
{
    constexpr int NKS = 8;
    const int tid = threadIdx.x;
    const int wid = tid >> 6;
    const int lane = tid & 63;
    const int g = lane >> 4, r16 = lane & 15;
    const int i0 = blockIdx.x * 32;
    const int c0 = wid * 64;

    f32x4 acc[2][4];
    #pragma unroll
    for (int rb = 0; rb < 2; ++rb)
        #pragma unroll
        for (int cf = 0; cf < 4; ++cf)
            acc[rb][cf] = (f32x4){0.f, 0.f, 0.f, 0.f};

    #pragma unroll
    for (int ks = 0; ks < NKS; ++ks) {
        short8 a[2];
        #pragma unroll
        for (int rb = 0; rb < 2; ++rb) {
            const int row = i0 + rb * 16 + r16;
            const int kk = ks * 32 + g * 8;
            a[rb] = (ks < NKS / 2)
                ? *(const short8*)(A1 + (size_t)row * IN_SIZE + kk)
                : *(const short8*)(A2 + (size_t)row * IN_SIZE + (kk - IN_SIZE));
        }
        short8 b[4];
        #pragma unroll
        for (int cf = 0; cf < 4; ++cf) {
            const int col = c0 + cf * 16 + r16;
            b[cf] = *(const short8*)(Wp + ((size_t)ks * 256 + col) * 32 + g * 8);
        }
        #pragma unroll
        for (int rb = 0; rb < 2; ++rb)
            #pragma unroll
            for (int cf = 0; cf < 4; ++cf)
                acc[rb][cf] = __builtin_amdgcn_mfma_f32_16x16x32_bf16(
                    a[rb], b[cf], acc[rb][cf], 0, 0, 0);
    }

    #pragma unroll
    for (int cf = 0; cf < 4; ++cf) {
        const int col = c0 + cf * 16 + r16;
        const float bv = bias[col];
        #pragma unroll
        for (int rb = 0; rb < 2; ++rb)
            #pragma unroll
            for (int rr = 0; rr < 4; ++rr) {
                const int row = i0 + rb * 16 + g * 4 + rr;
                out[(size_t)row * HID + col] = f2bf(fmaxf(acc[rb][cf][rr] + bv, 0.0f));
            }
    }
}

// ---------------- layer-2 fused pull + MFMA GEMM ----------------
__global__ __launch_bounds__(256) void k_sage2(
    const unsigned short* __restrict__ h,   // [N_DST1][256] bf16
    const int* __restrict__ rp, const int* __restrict__ csr,
    const unsigned short* __restrict__ Wp,
    const float* __restrict__ bias,
    float* __restrict__ out)                // [N_DST2][256] f32
{
    __shared__ __align__(16) unsigned short At[32][264];
    const int tid = threadIdx.x;
    const int wid = tid >> 6;
    const int lane = tid & 63;
    const int i0 = blockIdx.x * 32;

    for (int r = 0; r < 8; ++r) {
        const int row = wid * 8 + r;
        const int d = i0 + row;
        const int beg = rp[d], end = rp[d + 1];
        float a0 = 0.f, a1 = 0.f, a2 = 0.f, a3 = 0.f;
        const unsigned short* hb = h + lane * 4;
        int j = beg;
        for (; j + 3 < end; j += 4) {
            const uint2 va = *(const uint2*)(hb + (size_t)csr[j + 0] * HID);
            const uint2 vb = *(const uint2*)(hb + (size_t)csr[j + 1] * HID);
            const uint2 vc = *(const uint2*)(hb + (size_t)csr[j + 2] * HID);
            const uint2 vd = *(const uint2*)(hb + (size_t)csr[j + 3] * HID);
            a0 += (bf2f(va.x) + bf2f(vb.x)) + (bf2f(vc.x) + bf2f(vd.x));
            a1 += (bf2f(va.x >> 16) + bf2f(vb.x >> 16)) + (bf2f(vc.x >> 16) + bf2f(vd.x >> 16));
            a2 += (bf2f(va.y) + bf2f(vb.y)) + (bf2f(vc.y) + bf2f(vd.y));
            a3 += (bf2f(va.y >> 16) + bf2f(vb.y >> 16)) + (bf2f(vc.y >> 16) + bf2f(vd.y >> 16));
        }
        for (; j < end; ++j) {
            const uint2 va = *(const uint2*)(hb + (size_t)csr[j] * HID);
            a0 += bf2f(va.x); a1 += bf2f(va.x >> 16);
            a2 += bf2f(va.y); a3 += bf2f(va.y >> 16);
        }
        const float inv = 1.0f / fmaxf((float)(end - beg), 1.0f);
        uint2 o;
        o.x = (unsigned)f2bf(a0 * inv) | ((unsigned)f2bf(a1 * inv) << 16);
        o.y = (unsigned)f2bf(a2 * inv) | ((unsigned)f2bf(a3 * inv) << 16);
        *(uint2*)&At[row][lane * 4] = o;
    }
    __syncthreads();

    const int g = lane >> 4, r16 = lane & 15;
    const int c0 = wid * 64;
    f32x4 acc[2][4];
    #pragma unroll
    for (int rb = 0; rb < 2; ++rb)
        #pragma unroll
        for (int cf = 0; cf < 4; ++cf)
            acc[rb][cf] = (f32x4){0.f, 0.f, 0.f, 0.f};

    #pragma unroll
    for (int ks = 0; ks < 16; ++ks) {
        short8 a[2];
        #pragma unroll
        for (int rb = 0; rb < 2; ++rb) {
            const int row16 = rb * 16 + r16;
            if (ks < 8)
                a[rb] = *(const short8*)(h + (size_t)(i0 + row16) * HID + ks * 32 + g * 8);
            else
                a[rb] = *(const short8*)&At[row16][(ks - 8) * 32 + g * 8];
        }
        short8 b[4];
        #pragma unroll
        for (int cf = 0; cf < 4; ++cf) {
            const int col = c0 + cf * 16 + r16;
            b[cf] = *(const short8*)(Wp + ((size_t)ks * 256 + col) * 32 + g * 8);
        }
        #pragma unroll
        for (int rb = 0; rb < 2; ++rb)
            #pragma unroll
            for (int cf = 0; cf < 4; ++cf)
                acc[rb][cf] = __builtin_amdgcn_mfma_f32_16x16x32_bf16(
                    a[rb], b[cf], acc[rb][cf], 0, 0, 0);
    }

    #pragma unroll
    for (int cf = 0; cf < 4; ++cf) {
        const int col = c0 + cf * 16 + r16;
        const float bv = bias[col];
        #pragma unroll
        for (int rb = 0; rb < 2; ++rb)
            #pragma unroll
            for (int rr = 0; rr < 4; ++rr) {
                const int row = i0 + rb * 16 + g * 4 + rr;
                out[(size_t)row * HID + col] = acc[rb][cf][rr] + bv;
            }
    }
}

extern "C" void kernel_launch(void* const* d_in, const int* in_sizes, int n_in,
                              void* d_out, int out_size, void* d_ws, size_t ws_size,
                              hipStream_t stream) {
    const float* x       = (const float*)d_in[0];
    const int*   src1    = (const int*)d_in[1];
    const int*   dst1    = (const int*)d_in[2];
    const int*   src2    = (const int*)d_in[3];
    const int*   dst2    = (const int*)d_in[4];
    const float* W_self1 = (const float*)d_in[5];
    const float* W_neigh1= (const float*)d_in[6];
    const float* b1      = (const float*)d_in[7];
    const float* W_self2 = (const float*)d_in[8];
    const float* W_neigh2= (const float*)d_in[9];
    const float* b2      = (const float*)d_in[10];
    float* out = (float*)d_out;

    char* ws = (char*)d_ws;
    unsigned short* xbf  = (unsigned short*)(ws + OFF_XBF);
    unsigned short* h    = (unsigned short*)(ws + OFF_H);
    unsigned short* msg1 = (unsigned short*)(ws + OFF_MSG1);
    unsigned* stg1 = (unsigned*)(ws + OFF_STG1);
    unsigned* stg2 = (unsigned*)(ws + OFF_STG2);
    int* bp1  = (int*)(ws + OFF_BP1);
    int* bp2  = (int*)(ws + OFF_BP2);
    int* bt1  = (int*)(ws + OFF_BT1);
    int* bt2  = (int*)(ws + OFF_BT2);
    int* rp1  = (int*)(ws + OFF_RP1);
    int* rp2  = (int*)(ws + OFF_RP2);
    int* csr1 = (int*)(ws + OFF_CSR1);
    int* csr2 = (int*)(ws + OFF_CSR2);
    unsigned short* wp1 = (unsigned short*)(ws + OFF_WP1);
    unsigned short* wp2 = (unsigned short*)(ws + OFF_WP2);

    k_main1<<<MB_TOTAL, 256, 0, stream>>>(x, xbf, dst1, bp1, dst2, bp2,
                                          W_self1, W_neigh1, wp1,
                                          W_self2, W_neigh2, wp2);
    k_scan_offs<<<NBIN1 + NBIN2, 256, 0, stream>>>(bp1, bp1, bt1, bp2, bp2, bt2);
    k_place<<<P1B1 + P1B2, 256, 0, stream>>>(src1, dst1, bp1, bt1, stg1,
                                             src2, dst2, bp2, bt2, stg2);
    k_fill_p2b<<<NBIN1 + NBIN2, 512, 0, stream>>>(stg1, bt1, rp1, csr1,
                                                  stg2, bt2, rp2, csr2);

    k_pull1<<<N_DST1 / 8, 256, 0, stream>>>(xbf, rp1, csr1, msg1);
    k_gemm1<<<N_DST1 / 32, 256, 0, stream>>>(xbf, msg1, wp1, b1, h);
    k_sage2<<<N_DST2 / 32, 256, 0, stream>>>(h, rp2, csr2, wp2, b2, out);
}

// Round 12
// 306.128 us; speedup vs baseline: 1.0109x; 1.0109x over previous
//
#include <hip/hip_runtime.h>

#define IN_SIZE 128
#define HID 256
#define N_SRC1 500000
#define N_DST1 100000
#define E1 1600000
#define N_DST2 16384
#define E2 262144

// radix fill: bins of 512 dst, atomic-free (hist -> offsets -> place -> sort)
#define NBIN1 196          // ceil(100000/512)
#define NBIN2 32           // 16384/512
#define P1B1  800          // layer-1 blocks, chunk = E1/800 = 2000 edges
#define P1B2  256          // layer-2 blocks, chunk = E2/256 = 1024 edges

// k_main1 block roles: [0,1056) hist, [1056,1152) pack, [1152,3456) cast
#define MB_HIST (P1B1 + P1B2)       // 1056
#define MB_PACK 96
#define MB_CAST 2304
#define MB_TOTAL (MB_HIST + MB_PACK + MB_CAST)   // 3456

// ---------------- workspace layout (bytes), total 221,220,224 ----------------
// ws_size ~= 1.02 GB (harness poison), no aliasing anywhere.
#define OFF_XBF  0ull           // xbf [500000][128] bf16 (128,000,000)
#define OFF_H    128000000ull   // h [100000][256] bf16   (51,200,000)
#define OFF_MSG1 179200000ull   // msg1 [100000][128] bf16 (25,600,000)
#define OFF_STG1 204800000ull   // staging1 [1.6M] u32    (6,400,000)
#define OFF_STG2 211200000ull   // staging2 [262144] u32  (1,048,576)
#define OFF_BP1  212248576ull   // hist/blkpref1 [800][196] i32 (627,200)
#define OFF_BP2  212875776ull   // hist/blkpref2 [256][32] i32  (32,768)
#define OFF_BT1  212908544ull   // bin totals1 (1,024)
#define OFF_BT2  212909568ull   // bin totals2 (1,024)
#define OFF_RP1  212912640ull   // rowptr1 [100001] i32 (400,128)
#define OFF_RP2  213312768ull   // rowptr2 [16385] i32  (65,664)
#define OFF_CSR1 213378432ull   // csr1 [1,600,000] i32 (6,400,000)
#define OFF_CSR2 219778432ull   // csr2 [262,144] i32   (1,048,576)
#define OFF_WP1  220827008ull   // packed W1 bf16 (131,072)
#define OFF_WP2  220958080ull   // packed W2 bf16 (262,144)

typedef __attribute__((ext_vector_type(8))) short short8;
typedef __attribute__((ext_vector_type(4))) float f32x4;

__device__ __forceinline__ unsigned short f2bf(float f) {
    unsigned u = __float_as_uint(f);
    return (unsigned short)((u + 0x7FFFu + ((u >> 16) & 1u)) >> 16);
}
__device__ __forceinline__ float bf2f(unsigned short b) {
    return __uint_as_float(((unsigned)b) << 16);
}

// ---------------- fused: bin-histograms | weight-pack | streaming cast ----------------
__global__ __launch_bounds__(256) void k_main1(
    const float* __restrict__ x, unsigned short* __restrict__ xbf,
    const int* __restrict__ dst1, int* __restrict__ hist1,
    const int* __restrict__ dst2, int* __restrict__ hist2,
    const float* __restrict__ Ws1, const float* __restrict__ Wn1,
    unsigned short* __restrict__ wp1,
    const float* __restrict__ Ws2, const float* __restrict__ Wn2,
    unsigned short* __restrict__ wp2)
{
    __shared__ int lcnt[NBIN1];
    const int bid = blockIdx.x;
    const int tid = threadIdx.x;

    if (bid < MB_HIST) {
        const bool l1 = bid < P1B1;
        const int blk = l1 ? bid : bid - P1B1;
        const int nbins = l1 ? NBIN1 : NBIN2;
        const int chunk = l1 ? (E1 / P1B1) : (E2 / P1B2);
        const int* dst = l1 ? dst1 : dst2;
        int* hist = l1 ? hist1 : hist2;
        const int e0 = blk * chunk;
        for (int i = tid; i < nbins; i += 256) lcnt[i] = 0;
        __syncthreads();
        for (int i = tid; i < chunk; i += 256)
            atomicAdd(&lcnt[dst[e0 + i] >> 9], 1);
        __syncthreads();
        for (int i = tid; i < nbins; i += 256)
            hist[blk * nbins + i] = lcnt[i];     // coalesced
    } else if (bid < MB_HIST + MB_PACK) {
        const int pb = bid - MB_HIST;
        const bool l1 = pb < 32;
        const int Keach = l1 ? 128 : 256;
        const float* Wa = l1 ? Ws1 : Ws2;
        const float* Wb = l1 ? Wn1 : Wn2;
        unsigned short* outp = l1 ? wp1 : wp2;
        const int t = (l1 ? pb : pb - 32) * 256 + tid;
        const int kb = t >> 10;
        const int c  = (t >> 2) & 255;
        const int g  = t & 3;
        const int kbase = kb * 32 + g * 8;
        const float* W = (kbase < Keach) ? (Wa + (size_t)kbase * HID + c)
                                         : (Wb + (size_t)(kbase - Keach) * HID + c);
        unsigned short* o = outp + ((size_t)kb * 256 + c) * 32 + g * 8;
        #pragma unroll
        for (int j = 0; j < 8; ++j) o[j] = f2bf(W[(size_t)j * HID]);
    } else {
        const int cb = bid - MB_HIST - MB_PACK;
        const int T = MB_CAST * 256;
        const float4* x4 = (const float4*)x;
        short8* o8 = (short8*)xbf;
        for (int i = cb * 256 + tid; i < N_SRC1 * IN_SIZE / 8; i += T) {
            const float4 u0 = x4[(size_t)i * 2];
            const float4 u1 = x4[(size_t)i * 2 + 1];
            short8 o;
            o[0] = (short)f2bf(u0.x); o[1] = (short)f2bf(u0.y);
            o[2] = (short)f2bf(u0.z); o[3] = (short)f2bf(u0.w);
            o[4] = (short)f2bf(u1.x); o[5] = (short)f2bf(u1.y);
            o[6] = (short)f2bf(u1.z); o[7] = (short)f2bf(u1.w);
            o8[i] = o;
        }
    }
}

// ---------------- radix B: per-bin block-prefix + bin totals ----------------
__global__ __launch_bounds__(256) void k_scan_offs(
    const int* __restrict__ hist1, int* __restrict__ blkpref1, int* __restrict__ bintot1,
    const int* __restrict__ hist2, int* __restrict__ blkpref2, int* __restrict__ bintot2)
{
    __shared__ int s[256];
    const int tid = threadIdx.x;
    const bool l1 = blockIdx.x < NBIN1;
    const int b = l1 ? blockIdx.x : blockIdx.x - NBIN1;
    const int nblk = l1 ? P1B1 : P1B2;
    const int nbins = l1 ? NBIN1 : NBIN2;
    const int* hist = l1 ? hist1 : hist2;
    int* blkpref = l1 ? blkpref1 : blkpref2;
    int* bintot = l1 ? bintot1 : bintot2;

    int v[4];
    int lsum = 0;
    #pragma unroll
    for (int j = 0; j < 4; ++j) {
        const int idx = tid * 4 + j;
        v[j] = (idx < nblk) ? hist[idx * nbins + b] : 0;
        lsum += v[j];
    }
    s[tid] = lsum;
    __syncthreads();
    for (int off = 1; off < 256; off <<= 1) {
        int t = (tid >= off) ? s[tid - off] : 0;
        __syncthreads();
        s[tid] += t;
        __syncthreads();
    }
    int run = s[tid] - lsum;
    #pragma unroll
    for (int j = 0; j < 4; ++j) {
        const int idx = tid * 4 + j;
        if (idx < nblk) blkpref[idx * nbins + b] = run;
        run += v[j];
    }
    if (tid == 255) bintot[b] = s[255];
}

// ---------------- radix C: place packed entries at precomputed slots ----------------
__global__ __launch_bounds__(256) void k_place(
    const int* __restrict__ src1, const int* __restrict__ dst1,
    const int* __restrict__ blkpref1, const int* __restrict__ bintot1,
    unsigned* __restrict__ stg1,
    const int* __restrict__ src2, const int* __restrict__ dst2,
    const int* __restrict__ blkpref2, const int* __restrict__ bintot2,
    unsigned* __restrict__ stg2)
{
    __shared__ int lcur[NBIN1];
    __shared__ int sp[256];
    const int tid = threadIdx.x;
    const bool l1 = blockIdx.x < P1B1;
    const int blk = l1 ? blockIdx.x : blockIdx.x - P1B1;
    const int nbins = l1 ? NBIN1 : NBIN2;
    const int chunk = l1 ? (E1 / P1B1) : (E2 / P1B2);
    const int* src = l1 ? src1 : src2;
    const int* dst = l1 ? dst1 : dst2;
    const int* blkpref = l1 ? blkpref1 : blkpref2;
    const int* bintot = l1 ? bintot1 : bintot2;
    unsigned* stg = l1 ? stg1 : stg2;
    const int e0 = blk * chunk;

    const int bv = (tid < nbins) ? bintot[tid] : 0;
    sp[tid] = bv;
    __syncthreads();
    for (int off = 1; off < 256; off <<= 1) {
        int t = (tid >= off) ? sp[tid - off] : 0;
        __syncthreads();
        sp[tid] += t;
        __syncthreads();
    }
    if (tid < nbins) lcur[tid] = (sp[tid] - bv) + blkpref[blk * nbins + tid];
    __syncthreads();

    for (int i = tid; i < chunk; i += 256) {
        const int e = e0 + i;
        const int d = dst[e];
        const unsigned pk = ((unsigned)(d & 511) << 19) | (unsigned)src[e];
        const int pos = atomicAdd(&lcur[d >> 9], 1);
        stg[pos] = pk;
    }
}

// ---------------- radix D: per-bin hist -> scan -> rowptr -> counting sort ----------------
__global__ __launch_bounds__(512) void k_fill_p2b(
    const unsigned* __restrict__ stg1, const int* __restrict__ bintot1,
    int* __restrict__ rp1, int* __restrict__ csr1,
    const unsigned* __restrict__ stg2, const int* __restrict__ bintot2,
    int* __restrict__ rp2, int* __restrict__ csr2)
{
    __shared__ int lcnt[512];
    __shared__ int s[512];
    __shared__ int rbv[2];
    const int tid = threadIdx.x;
    const bool l1 = blockIdx.x < NBIN1;
    const int b = l1 ? blockIdx.x : blockIdx.x - NBIN1;
    const int base = b << 9;
    const int ndst = l1 ? N_DST1 : N_DST2;
    const int nbins = l1 ? NBIN1 : NBIN2;
    const int nr = min(512, ndst - base);
    const unsigned* stg = l1 ? stg1 : stg2;
    const int* bintot = l1 ? bintot1 : bintot2;
    int* rp = l1 ? rp1 : rp2;
    int* csr = l1 ? csr1 : csr2;

    const int bv = (tid < nbins) ? bintot[tid] : 0;
    s[tid] = bv;
    __syncthreads();
    for (int off = 1; off < 512; off <<= 1) {
        int t = (tid >= off) ? s[tid - off] : 0;
        __syncthreads();
        s[tid] += t;
        __syncthreads();
    }
    if (tid == b) { rbv[0] = s[tid] - bv; rbv[1] = s[tid]; }
    __syncthreads();
    const int s0 = rbv[0], s1 = rbv[1];

    lcnt[tid] = 0;
    __syncthreads();
    for (int i = s0 + tid; i < s1; i += 512)
        atomicAdd(&lcnt[stg[i] >> 19], 1);
    __syncthreads();

    const int v = lcnt[tid];
    s[tid] = v;
    __syncthreads();
    for (int off = 1; off < 512; off <<= 1) {
        int t = (tid >= off) ? s[tid - off] : 0;
        __syncthreads();
        s[tid] += t;
        __syncthreads();
    }
    const int excl = s0 + s[tid] - v;
    if (tid < nr) rp[base + tid] = excl;
    if (base + tid == ndst - 1) rp[ndst] = s1;
    __syncthreads();
    lcnt[tid] = excl;          // reuse as cursor
    __syncthreads();

    for (int i = s0 + tid; i < s1; i += 512) {
        const unsigned pk = stg[i];
        const int pos = atomicAdd(&lcnt[pk >> 19], 1);
        csr[pos] = (int)(pk & 0x7FFFFu);
    }
}

// ---------------- layer-1 pull (quarter-wave per dst, uint4 loads, 8 deep) ----------------
// 16 lanes per dst; lane loads uint4 = 16B = 8 bf16 cols; 16*8 = 128 cols.
// 4 dst/wave, 16 dst/block -> 2x dst-parallelism and 2x bytes/load vs half-wave.
__global__ __launch_bounds__(256) void k_pull1(
    const unsigned short* __restrict__ xbf, const int* __restrict__ rp,
    const int* __restrict__ csr, unsigned short* __restrict__ msg)
{
    const int d = blockIdx.x * 16 + (threadIdx.x >> 4);
    const int ql = threadIdx.x & 15;
    const int beg = rp[d], end = rp[d + 1];
    float a0 = 0.f, a1 = 0.f, a2 = 0.f, a3 = 0.f;
    float a4 = 0.f, a5 = 0.f, a6 = 0.f, a7 = 0.f;
    const unsigned short* xb = xbf + ql * 8;
    int j = beg;
    for (; j + 7 < end; j += 8) {
        const uint4 v0 = *(const uint4*)(xb + (size_t)csr[j + 0] * IN_SIZE);
        const uint4 v1 = *(const uint4*)(xb + (size_t)csr[j + 1] * IN_SIZE);
        const uint4 v2 = *(const uint4*)(xb + (size_t)csr[j + 2] * IN_SIZE);
        const uint4 v3 = *(const uint4*)(xb + (size_t)csr[j + 3] * IN_SIZE);
        const uint4 v4 = *(const uint4*)(xb + (size_t)csr[j + 4] * IN_SIZE);
        const uint4 v5 = *(const uint4*)(xb + (size_t)csr[j + 5] * IN_SIZE);
        const uint4 v6 = *(const uint4*)(xb + (size_t)csr[j + 6] * IN_SIZE);
        const uint4 v7 = *(const uint4*)(xb + (size_t)csr[j + 7] * IN_SIZE);
        a0 += ((bf2f(v0.x) + bf2f(v1.x)) + (bf2f(v2.x) + bf2f(v3.x)))
            + ((bf2f(v4.x) + bf2f(v5.x)) + (bf2f(v6.x) + bf2f(v7.x)));
        a1 += ((bf2f(v0.x >> 16) + bf2f(v1.x >> 16)) + (bf2f(v2.x >> 16) + bf2f(v3.x >> 16)))
            + ((bf2f(v4.x >> 16) + bf2f(v5.x >> 16)) + (bf2f(v6.x >> 16) + bf2f(v7.x >> 16)));
        a2 += ((bf2f(v0.y) + bf2f(v1.y)) + (bf2f(v2.y) + bf2f(v3.y)))
            + ((bf2f(v4.y) + bf2f(v5.y)) + (bf2f(v6.y) + bf2f(v7.y)));
        a3 += ((bf2f(v0.y >> 16) + bf2f(v1.y >> 16)) + (bf2f(v2.y >> 16) + bf2f(v3.y >> 16)))
            + ((bf2f(v4.y >> 16) + bf2f(v5.y >> 16)) + (bf2f(v6.y >> 16) + bf2f(v7.y >> 16)));
        a4 += ((bf2f(v0.z) + bf2f(v1.z)) + (bf2f(v2.z) + bf2f(v3.z)))
            + ((bf2f(v4.z) + bf2f(v5.z)) + (bf2f(v6.z) + bf2f(v7.z)));
        a5 += ((bf2f(v0.z >> 16) + bf2f(v1.z >> 16)) + (bf2f(v2.z >> 16) + bf2f(v3.z >> 16)))
            + ((bf2f(v4.z >> 16) + bf2f(v5.z >> 16)) + (bf2f(v6.z >> 16) + bf2f(v7.z >> 16)));
        a6 += ((bf2f(v0.w) + bf2f(v1.w)) + (bf2f(v2.w) + bf2f(v3.w)))
            + ((bf2f(v4.w) + bf2f(v5.w)) + (bf2f(v6.w) + bf2f(v7.w)));
        a7 += ((bf2f(v0.w >> 16) + bf2f(v1.w >> 16)) + (bf2f(v2.w >> 16) + bf2f(v3.w >> 16)))
            + ((bf2f(v4.w >> 16) + bf2f(v5.w >> 16)) + (bf2f(v6.w >> 16) + bf2f(v7.w >> 16)));
    }
    for (; j < end; ++j) {
        const uint4 v = *(const uint4*)(xb + (size_t)csr[j] * IN_SIZE);
        a0 += bf2f(v.x); a1 += bf2f(v.x >> 16);
        a2 += bf2f(v.y); a3 += bf2f(v.y >> 16);
        a4 += bf2f(v.z); a5 += bf2f(v.z >> 16);
        a6 += bf2f(v.w); a7 += bf2f(v.w >> 16);
    }
    const float inv = 1.0f / fmaxf((float)(end - beg), 1.0f);
    uint4 o;
    o.x = (unsigned)f2bf(a0 * inv) | ((unsigned)f2bf(a1 * inv) << 16);
    o.y = (unsigned)f2bf(a2 * inv) | ((unsigned)f2bf(a3 * inv) << 16);
    o.z = (unsigned)f2bf(a4 * inv) | ((unsigned)f2bf(a5 * inv) << 16);
    o.w = (unsigned)f2bf(a6 * inv) | ((unsigned)f2bf(a7 * inv) << 16);
    *(uint4*)(msg + (size_t)d * IN_SIZE + ql * 8) = o;
}

// ---------------- layer-1 MFMA GEMM ----------------
__global__ __launch_bounds__(256) void k_gemm1(
    const unsigned short* __restrict__ A1,  // xbf [M][128]
    const unsigned short* __restrict__ A2,  // msg1 [M][128]
    const unsigned short* __restrict__ Wp,
    const float* __restrict__ bias,
    unsigned short* __restrict__ out)       // h bf16 [M][256]
{
    constexpr int NKS = 8;
    const int tid = threadIdx.x;
    const int wid = tid >> 6;
    const int lane = tid & 63;
    const int g = lane >> 4, r16 = lane & 15;
    const int i0 = blockIdx.x * 32;
    const int c0 = wid * 64;

    f32x4 acc[2][4];
    #pragma unroll
    for (int rb = 0; rb < 2; ++rb)
        #pragma unroll
        for (int cf = 0; cf < 4; ++cf)
            acc[rb][cf] = (f32x4){0.f, 0.f, 0.f, 0.f};

    #pragma unroll
    for (int ks = 0; ks < NKS; ++ks) {
        short8 a[2];
        #pragma unroll
        for (int rb = 0; rb < 2; ++rb) {
            const int row = i0 + rb * 16 + r16;
            const int kk = ks * 32 + g * 8;
            a[rb] = (ks < NKS / 2)
                ? *(const short8*)(A1 + (size_t)row * IN_SIZE + kk)
                : *(const short8*)(A2 + (size_t)row * IN_SIZE + (kk - IN_SIZE));
        }
        short8 b[4];
        #pragma unroll
        for (int cf = 0; cf < 4; ++cf) {
            const int col = c0 + cf * 16 + r16;
            b[cf] = *(const short8*)(Wp + ((size_t)ks * 256 + col) * 32 + g * 8);
        }
        #pragma unroll
        for (int rb = 0; rb < 2; ++rb)
            #pragma unroll
            for (int cf = 0; cf < 4; ++cf)
                acc[rb][cf] = __builtin_amdgcn_mfma_f32_16x16x32_bf16(
                    a[rb], b[cf], acc[rb][cf], 0, 0, 0);
    }

    #pragma unroll
    for (int cf = 0; cf < 4; ++cf) {
        const int col = c0 + cf * 16 + r16;
        const float bv = bias[col];
        #pragma unroll
        for (int rb = 0; rb < 2; ++rb)
            #pragma unroll
            for (int rr = 0; rr < 4; ++rr) {
                const int row = i0 + rb * 16 + g * 4 + rr;
                out[(size_t)row * HID + col] = f2bf(fmaxf(acc[rb][cf][rr] + bv, 0.0f));
            }
    }
}

// ---------------- layer-2 fused pull + MFMA GEMM ----------------
__global__ __launch_bounds__(256) void k_sage2(
    const unsigned short* __restrict__ h,   // [N_DST1][256] bf16
    const int* __restrict__ rp, const int* __restrict__ csr,
    const unsigned short* __restrict__ Wp,
    const float* __restrict__ bias,
    float* __restrict__ out)                // [N_DST2][256] f32
{
    __shared__ __align__(16) unsigned short At[32][264];
    const int tid = threadIdx.x;
    const int wid = tid >> 6;
    const int lane = tid & 63;
    const int i0 = blockIdx.x * 32;

    for (int r = 0; r < 8; ++r) {
        const int row = wid * 8 + r;
        const int d = i0 + row;
        const int beg = rp[d], end = rp[d + 1];
        float a0 = 0.f, a1 = 0.f, a2 = 0.f, a3 = 0.f;
        const unsigned short* hb = h + lane * 4;
        int j = beg;
        for (; j + 3 < end; j += 4) {
            const uint2 va = *(const uint2*)(hb + (size_t)csr[j + 0] * HID);
            const uint2 vb = *(const uint2*)(hb + (size_t)csr[j + 1] * HID);
            const uint2 vc = *(const uint2*)(hb + (size_t)csr[j + 2] * HID);
            const uint2 vd = *(const uint2*)(hb + (size_t)csr[j + 3] * HID);
            a0 += (bf2f(va.x) + bf2f(vb.x)) + (bf2f(vc.x) + bf2f(vd.x));
            a1 += (bf2f(va.x >> 16) + bf2f(vb.x >> 16)) + (bf2f(vc.x >> 16) + bf2f(vd.x >> 16));
            a2 += (bf2f(va.y) + bf2f(vb.y)) + (bf2f(vc.y) + bf2f(vd.y));
            a3 += (bf2f(va.y >> 16) + bf2f(vb.y >> 16)) + (bf2f(vc.y >> 16) + bf2f(vd.y >> 16));
        }
        for (; j < end; ++j) {
            const uint2 va = *(const uint2*)(hb + (size_t)csr[j] * HID);
            a0 += bf2f(va.x); a1 += bf2f(va.x >> 16);
            a2 += bf2f(va.y); a3 += bf2f(va.y >> 16);
        }
        const float inv = 1.0f / fmaxf((float)(end - beg), 1.0f);
        uint2 o;
        o.x = (unsigned)f2bf(a0 * inv) | ((unsigned)f2bf(a1 * inv) << 16);
        o.y = (unsigned)f2bf(a2 * inv) | ((unsigned)f2bf(a3 * inv) << 16);
        *(uint2*)&At[row][lane * 4] = o;
    }
    __syncthreads();

    const int g = lane >> 4, r16 = lane & 15;
    const int c0 = wid * 64;
    f32x4 acc[2][4];
    #pragma unroll
    for (int rb = 0; rb < 2; ++rb)
        #pragma unroll
        for (int cf = 0; cf < 4; ++cf)
            acc[rb][cf] = (f32x4){0.f, 0.f, 0.f, 0.f};

    #pragma unroll
    for (int ks = 0; ks < 16; ++ks) {
        short8 a[2];
        #pragma unroll
        for (int rb = 0; rb < 2; ++rb) {
            const int row16 = rb * 16 + r16;
            if (ks < 8)
                a[rb] = *(const short8*)(h + (size_t)(i0 + row16) * HID + ks * 32 + g * 8);
            else
                a[rb] = *(const short8*)&At[row16][(ks - 8) * 32 + g * 8];
        }
        short8 b[4];
        #pragma unroll
        for (int cf = 0; cf < 4; ++cf) {
            const int col = c0 + cf * 16 + r16;
            b[cf] = *(const short8*)(Wp + ((size_t)ks * 256 + col) * 32 + g * 8);
        }
        #pragma unroll
        for (int rb = 0; rb < 2; ++rb)
            #pragma unroll
            for (int cf = 0; cf < 4; ++cf)
                acc[rb][cf] = __builtin_amdgcn_mfma_f32_16x16x32_bf16(
                    a[rb], b[cf], acc[rb][cf], 0, 0, 0);
    }

    #pragma unroll
    for (int cf = 0; cf < 4; ++cf) {
        const int col = c0 + cf * 16 + r16;
        const float bv = bias[col];
        #pragma unroll
        for (int rb = 0; rb < 2; ++rb)
            #pragma unroll
            for (int rr = 0; rr < 4; ++rr) {
                const int row = i0 + rb * 16 + g * 4 + rr;
                out[(size_t)row * HID + col] = acc[rb][cf][rr] + bv;
            }
    }
}

extern "C" void kernel_launch(void* const* d_in, const int* in_sizes, int n_in,
                              void* d_out, int out_size, void* d_ws, size_t ws_size,
                              hipStream_t stream) {
    const float* x       = (const float*)d_in[0];
    const int*   src1    = (const int*)d_in[1];
    const int*   dst1    = (const int*)d_in[2];
    const int*   src2    = (const int*)d_in[3];
    const int*   dst2    = (const int*)d_in[4];
    const float* W_self1 = (const float*)d_in[5];
    const float* W_neigh1= (const float*)d_in[6];
    const float* b1      = (const float*)d_in[7];
    const float* W_self2 = (const float*)d_in[8];
    const float* W_neigh2= (const float*)d_in[9];
    const float* b2      = (const float*)d_in[10];
    float* out = (float*)d_out;

    char* ws = (char*)d_ws;
    unsigned short* xbf  = (unsigned short*)(ws + OFF_XBF);
    unsigned short* h    = (unsigned short*)(ws + OFF_H);
    unsigned short* msg1 = (unsigned short*)(ws + OFF_MSG1);
    unsigned* stg1 = (unsigned*)(ws + OFF_STG1);
    unsigned* stg2 = (unsigned*)(ws + OFF_STG2);
    int* bp1  = (int*)(ws + OFF_BP1);
    int* bp2  = (int*)(ws + OFF_BP2);
    int* bt1  = (int*)(ws + OFF_BT1);
    int* bt2  = (int*)(ws + OFF_BT2);
    int* rp1  = (int*)(ws + OFF_RP1);
    int* rp2  = (int*)(ws + OFF_RP2);
    int* csr1 = (int*)(ws + OFF_CSR1);
    int* csr2 = (int*)(ws + OFF_CSR2);
    unsigned short* wp1 = (unsigned short*)(ws + OFF_WP1);
    unsigned short* wp2 = (unsigned short*)(ws + OFF_WP2);

    k_main1<<<MB_TOTAL, 256, 0, stream>>>(x, xbf, dst1, bp1, dst2, bp2,
                                          W_self1, W_neigh1, wp1,
                                          W_self2, W_neigh2, wp2);
    k_scan_offs<<<NBIN1 + NBIN2, 256, 0, stream>>>(bp1, bp1, bt1, bp2, bp2, bt2);
    k_place<<<P1B1 + P1B2, 256, 0, stream>>>(src1, dst1, bp1, bt1, stg1,
                                             src2, dst2, bp2, bt2, stg2);
    k_fill_p2b<<<NBIN1 + NBIN2, 512, 0, stream>>>(stg1, bt1, rp1, csr1,
                                                  stg2, bt2, rp2, csr2);

    k_pull1<<<N_DST1 / 16, 256, 0, stream>>>(xbf, rp1, csr1, msg1);
    k_gemm1<<<N_DST1 / 32, 256, 0, stream>>>(xbf, msg1, wp1, b1, h);
    k_sage2<<<N_DST2 / 32, 256, 0, stream>>>(h, rp2, csr2, wp2, b2, out);
}

// Round 13
// 288.417 us; speedup vs baseline: 1.0730x; 1.0614x over previous
//
#include <hip/hip_runtime.h>

#define IN_SIZE 128
#define HID 256
#define N_SRC1 500000
#define N_DST1 100000
#define E1 1600000
#define N_DST2 16384
#define E2 262144

// radix fill: bins of 512 dst, atomic-free (hist -> offsets -> place -> sort)
#define NBIN1 196          // ceil(100000/512)
#define NBIN2 32           // 16384/512
#define P1B1  800          // layer-1 blocks, chunk = E1/800 = 2000 edges
#define P1B2  256          // layer-2 blocks, chunk = E2/256 = 1024 edges

// cast work: 8M short8 groups, split into 4 slices of 2M riding on the 4 fill kernels
#define GRP_TOTAL 8000000
#define SLICE     2000000
#define CAST_A    2048     // cast blocks (256 thr) in k_fillA
#define CAST_B    2048     // in k_fillB
#define CAST_C    2048     // in k_fillC
#define CAST_D    1024     // in k_fillD (512 thr blocks)

// ---------------- workspace layout (bytes), total 221,220,224 ----------------
#define OFF_XBF  0ull           // xbf [500000][128] bf16 (128,000,000)
#define OFF_H    128000000ull   // h [100000][256] bf16   (51,200,000)
#define OFF_MSG1 179200000ull   // msg1 [100000][128] bf16 (25,600,000)
#define OFF_STG1 204800000ull   // staging1 [1.6M] u32    (6,400,000)
#define OFF_STG2 211200000ull   // staging2 [262144] u32  (1,048,576)
#define OFF_BP1  212248576ull   // hist/blkpref1 [800][196] i32 (627,200)
#define OFF_BP2  212875776ull   // hist/blkpref2 [256][32] i32  (32,768)
#define OFF_BT1  212908544ull   // bin totals1 (1,024)
#define OFF_BT2  212909568ull   // bin totals2 (1,024)
#define OFF_RP1  212912640ull   // rowptr1 [100001] i32 (400,128)
#define OFF_RP2  213312768ull   // rowptr2 [16385] i32  (65,664)
#define OFF_CSR1 213378432ull   // csr1 [1,600,000] i32 (6,400,000)
#define OFF_CSR2 219778432ull   // csr2 [262,144] i32   (1,048,576)
#define OFF_WP1  220827008ull   // packed W1 bf16 (131,072)
#define OFF_WP2  220958080ull   // packed W2 bf16 (262,144)

typedef __attribute__((ext_vector_type(8))) short short8;
typedef __attribute__((ext_vector_type(4))) float f32x4;

__device__ __forceinline__ unsigned short f2bf(float f) {
    unsigned u = __float_as_uint(f);
    return (unsigned short)((u + 0x7FFFu + ((u >> 16) & 1u)) >> 16);
}
__device__ __forceinline__ float bf2f(unsigned short b) {
    return __uint_as_float(((unsigned)b) << 16);
}

// streaming cast of short8-groups [idx0, end) with stride
__device__ __forceinline__ void cast_slice(const float* __restrict__ x,
                                           unsigned short* __restrict__ xbf,
                                           int idx0, int stride, int end)
{
    const float4* x4 = (const float4*)x;
    short8* o8 = (short8*)xbf;
    for (int i = idx0; i < end; i += stride) {
        const float4 u0 = x4[(size_t)i * 2];
        const float4 u1 = x4[(size_t)i * 2 + 1];
        short8 o;
        o[0] = (short)f2bf(u0.x); o[1] = (short)f2bf(u0.y);
        o[2] = (short)f2bf(u0.z); o[3] = (short)f2bf(u0.w);
        o[4] = (short)f2bf(u1.x); o[5] = (short)f2bf(u1.y);
        o[6] = (short)f2bf(u1.z); o[7] = (short)f2bf(u1.w);
        o8[i] = o;
    }
}

// ---------------- fillA: hist | pack | cast slice 0 ----------------
__global__ __launch_bounds__(256) void k_fillA(
    const float* __restrict__ x, unsigned short* __restrict__ xbf,
    const int* __restrict__ dst1, int* __restrict__ hist1,
    const int* __restrict__ dst2, int* __restrict__ hist2,
    const float* __restrict__ Ws1, const float* __restrict__ Wn1,
    unsigned short* __restrict__ wp1,
    const float* __restrict__ Ws2, const float* __restrict__ Wn2,
    unsigned short* __restrict__ wp2)
{
    __shared__ int lcnt[NBIN1];
    const int bid = blockIdx.x;
    const int tid = threadIdx.x;

    if (bid < P1B1 + P1B2) {
        const bool l1 = bid < P1B1;
        const int blk = l1 ? bid : bid - P1B1;
        const int nbins = l1 ? NBIN1 : NBIN2;
        const int chunk = l1 ? (E1 / P1B1) : (E2 / P1B2);
        const int* dst = l1 ? dst1 : dst2;
        int* hist = l1 ? hist1 : hist2;
        const int e0 = blk * chunk;
        for (int i = tid; i < nbins; i += 256) lcnt[i] = 0;
        __syncthreads();
        for (int i = tid; i < chunk; i += 256)
            atomicAdd(&lcnt[dst[e0 + i] >> 9], 1);
        __syncthreads();
        for (int i = tid; i < nbins; i += 256)
            hist[blk * nbins + i] = lcnt[i];     // coalesced
    } else if (bid < P1B1 + P1B2 + 96) {
        const int pb = bid - (P1B1 + P1B2);
        const bool l1 = pb < 32;
        const int Keach = l1 ? 128 : 256;
        const float* Wa = l1 ? Ws1 : Ws2;
        const float* Wb = l1 ? Wn1 : Wn2;
        unsigned short* outp = l1 ? wp1 : wp2;
        const int t = (l1 ? pb : pb - 32) * 256 + tid;
        const int kb = t >> 10;
        const int c  = (t >> 2) & 255;
        const int g  = t & 3;
        const int kbase = kb * 32 + g * 8;
        const float* W = (kbase < Keach) ? (Wa + (size_t)kbase * HID + c)
                                         : (Wb + (size_t)(kbase - Keach) * HID + c);
        unsigned short* o = outp + ((size_t)kb * 256 + c) * 32 + g * 8;
        #pragma unroll
        for (int j = 0; j < 8; ++j) o[j] = f2bf(W[(size_t)j * HID]);
    } else {
        const int cb = bid - (P1B1 + P1B2 + 96);
        cast_slice(x, xbf, 0 * SLICE + cb * 256 + tid, CAST_A * 256, 1 * SLICE);
    }
}

// ---------------- fillB: per-bin block-prefix + bin totals | cast slice 1 ----------------
__global__ __launch_bounds__(256) void k_fillB(
    const int* __restrict__ hist1, int* __restrict__ blkpref1, int* __restrict__ bintot1,
    const int* __restrict__ hist2, int* __restrict__ blkpref2, int* __restrict__ bintot2,
    const float* __restrict__ x, unsigned short* __restrict__ xbf)
{
    __shared__ int s[256];
    const int tid = threadIdx.x;
    if (blockIdx.x >= NBIN1 + NBIN2) {
        const int cb = blockIdx.x - (NBIN1 + NBIN2);
        cast_slice(x, xbf, 1 * SLICE + cb * 256 + tid, CAST_B * 256, 2 * SLICE);
        return;
    }
    const bool l1 = blockIdx.x < NBIN1;
    const int b = l1 ? blockIdx.x : blockIdx.x - NBIN1;
    const int nblk = l1 ? P1B1 : P1B2;
    const int nbins = l1 ? NBIN1 : NBIN2;
    const int* hist = l1 ? hist1 : hist2;
    int* blkpref = l1 ? blkpref1 : blkpref2;
    int* bintot = l1 ? bintot1 : bintot2;

    int v[4];
    int lsum = 0;
    #pragma unroll
    for (int j = 0; j < 4; ++j) {
        const int idx = tid * 4 + j;
        v[j] = (idx < nblk) ? hist[idx * nbins + b] : 0;
        lsum += v[j];
    }
    s[tid] = lsum;
    __syncthreads();
    for (int off = 1; off < 256; off <<= 1) {
        int t = (tid >= off) ? s[tid - off] : 0;
        __syncthreads();
        s[tid] += t;
        __syncthreads();
    }
    int run = s[tid] - lsum;
    #pragma unroll
    for (int j = 0; j < 4; ++j) {
        const int idx = tid * 4 + j;
        if (idx < nblk) blkpref[idx * nbins + b] = run;
        run += v[j];
    }
    if (tid == 255) bintot[b] = s[255];
}

// ---------------- fillC: place | cast slice 2 ----------------
__global__ __launch_bounds__(256) void k_fillC(
    const int* __restrict__ src1, const int* __restrict__ dst1,
    const int* __restrict__ blkpref1, const int* __restrict__ bintot1,
    unsigned* __restrict__ stg1,
    const int* __restrict__ src2, const int* __restrict__ dst2,
    const int* __restrict__ blkpref2, const int* __restrict__ bintot2,
    unsigned* __restrict__ stg2,
    const float* __restrict__ x, unsigned short* __restrict__ xbf)
{
    __shared__ int lcur[NBIN1];
    __shared__ int sp[256];
    const int tid = threadIdx.x;
    if (blockIdx.x >= P1B1 + P1B2) {
        const int cb = blockIdx.x - (P1B1 + P1B2);
        cast_slice(x, xbf, 2 * SLICE + cb * 256 + tid, CAST_C * 256, 3 * SLICE);
        return;
    }
    const bool l1 = blockIdx.x < P1B1;
    const int blk = l1 ? blockIdx.x : blockIdx.x - P1B1;
    const int nbins = l1 ? NBIN1 : NBIN2;
    const int chunk = l1 ? (E1 / P1B1) : (E2 / P1B2);
    const int* src = l1 ? src1 : src2;
    const int* dst = l1 ? dst1 : dst2;
    const int* blkpref = l1 ? blkpref1 : blkpref2;
    const int* bintot = l1 ? bintot1 : bintot2;
    unsigned* stg = l1 ? stg1 : stg2;
    const int e0 = blk * chunk;

    const int bv = (tid < nbins) ? bintot[tid] : 0;
    sp[tid] = bv;
    __syncthreads();
    for (int off = 1; off < 256; off <<= 1) {
        int t = (tid >= off) ? sp[tid - off] : 0;
        __syncthreads();
        sp[tid] += t;
        __syncthreads();
    }
    if (tid < nbins) lcur[tid] = (sp[tid] - bv) + blkpref[blk * nbins + tid];
    __syncthreads();

    for (int i = tid; i < chunk; i += 256) {
        const int e = e0 + i;
        const int d = dst[e];
        const unsigned pk = ((unsigned)(d & 511) << 19) | (unsigned)src[e];
        const int pos = atomicAdd(&lcur[d >> 9], 1);
        stg[pos] = pk;
    }
}

// ---------------- fillD: per-bin sort -> rowptr+csr | cast slice 3 (512 thr) ----------------
__global__ __launch_bounds__(512) void k_fillD(
    const unsigned* __restrict__ stg1, const int* __restrict__ bintot1,
    int* __restrict__ rp1, int* __restrict__ csr1,
    const unsigned* __restrict__ stg2, const int* __restrict__ bintot2,
    int* __restrict__ rp2, int* __restrict__ csr2,
    const float* __restrict__ x, unsigned short* __restrict__ xbf)
{
    __shared__ int lcnt[512];
    __shared__ int s[512];
    __shared__ int rbv[2];
    const int tid = threadIdx.x;
    if (blockIdx.x >= NBIN1 + NBIN2) {
        const int cb = blockIdx.x - (NBIN1 + NBIN2);
        cast_slice(x, xbf, 3 * SLICE + cb * 512 + tid, CAST_D * 512, 4 * SLICE);
        return;
    }
    const bool l1 = blockIdx.x < NBIN1;
    const int b = l1 ? blockIdx.x : blockIdx.x - NBIN1;
    const int base = b << 9;
    const int ndst = l1 ? N_DST1 : N_DST2;
    const int nbins = l1 ? NBIN1 : NBIN2;
    const int nr = min(512, ndst - base);
    const unsigned* stg = l1 ? stg1 : stg2;
    const int* bintot = l1 ? bintot1 : bintot2;
    int* rp = l1 ? rp1 : rp2;
    int* csr = l1 ? csr1 : csr2;

    const int bv = (tid < nbins) ? bintot[tid] : 0;
    s[tid] = bv;
    __syncthreads();
    for (int off = 1; off < 512; off <<= 1) {
        int t = (tid >= off) ? s[tid - off] : 0;
        __syncthreads();
        s[tid] += t;
        __syncthreads();
    }
    if (tid == b) { rbv[0] = s[tid] - bv; rbv[1] = s[tid]; }
    __syncthreads();
    const int s0 = rbv[0], s1 = rbv[1];

    lcnt[tid] = 0;
    __syncthreads();
    for (int i = s0 + tid; i < s1; i += 512)
        atomicAdd(&lcnt[stg[i] >> 19], 1);
    __syncthreads();

    const int v = lcnt[tid];
    s[tid] = v;
    __syncthreads();
    for (int off = 1; off < 512; off <<= 1) {
        int t = (tid >= off) ? s[tid - off] : 0;
        __syncthreads();
        s[tid] += t;
        __syncthreads();
    }
    const int excl = s0 + s[tid] - v;
    if (tid < nr) rp[base + tid] = excl;
    if (base + tid == ndst - 1) rp[ndst] = s1;
    __syncthreads();
    lcnt[tid] = excl;          // reuse as cursor
    __syncthreads();

    for (int i = s0 + tid; i < s1; i += 512) {
        const unsigned pk = stg[i];
        const int pos = atomicAdd(&lcnt[pk >> 19], 1);
        csr[pos] = (int)(pk & 0x7FFFFu);
    }
}

// ---------------- layer-1 pull (quarter-wave per dst, uint4 loads, 8 deep) ----------------
__global__ __launch_bounds__(256) void k_pull1(
    const unsigned short* __restrict__ xbf, const int* __restrict__ rp,
    const int* __restrict__ csr, unsigned short* __restrict__ msg)
{
    const int d = blockIdx.x * 16 + (threadIdx.x >> 4);
    const int ql = threadIdx.x & 15;
    const int beg = rp[d], end = rp[d + 1];
    float a0 = 0.f, a1 = 0.f, a2 = 0.f, a3 = 0.f;
    float a4 = 0.f, a5 = 0.f, a6 = 0.f, a7 = 0.f;
    const unsigned short* xb = xbf + ql * 8;
    int j = beg;
    for (; j + 7 < end; j += 8) {
        const uint4 v0 = *(const uint4*)(xb + (size_t)csr[j + 0] * IN_SIZE);
        const uint4 v1 = *(const uint4*)(xb + (size_t)csr[j + 1] * IN_SIZE);
        const uint4 v2 = *(const uint4*)(xb + (size_t)csr[j + 2] * IN_SIZE);
        const uint4 v3 = *(const uint4*)(xb + (size_t)csr[j + 3] * IN_SIZE);
        const uint4 v4 = *(const uint4*)(xb + (size_t)csr[j + 4] * IN_SIZE);
        const uint4 v5 = *(const uint4*)(xb + (size_t)csr[j + 5] * IN_SIZE);
        const uint4 v6 = *(const uint4*)(xb + (size_t)csr[j + 6] * IN_SIZE);
        const uint4 v7 = *(const uint4*)(xb + (size_t)csr[j + 7] * IN_SIZE);
        a0 += ((bf2f(v0.x) + bf2f(v1.x)) + (bf2f(v2.x) + bf2f(v3.x)))
            + ((bf2f(v4.x) + bf2f(v5.x)) + (bf2f(v6.x) + bf2f(v7.x)));
        a1 += ((bf2f(v0.x >> 16) + bf2f(v1.x >> 16)) + (bf2f(v2.x >> 16) + bf2f(v3.x >> 16)))
            + ((bf2f(v4.x >> 16) + bf2f(v5.x >> 16)) + (bf2f(v6.x >> 16) + bf2f(v7.x >> 16)));
        a2 += ((bf2f(v0.y) + bf2f(v1.y)) + (bf2f(v2.y) + bf2f(v3.y)))
            + ((bf2f(v4.y) + bf2f(v5.y)) + (bf2f(v6.y) + bf2f(v7.y)));
        a3 += ((bf2f(v0.y >> 16) + bf2f(v1.y >> 16)) + (bf2f(v2.y >> 16) + bf2f(v3.y >> 16)))
            + ((bf2f(v4.y >> 16) + bf2f(v5.y >> 16)) + (bf2f(v6.y >> 16) + bf2f(v7.y >> 16)));
        a4 += ((bf2f(v0.z) + bf2f(v1.z)) + (bf2f(v2.z) + bf2f(v3.z)))
            + ((bf2f(v4.z) + bf2f(v5.z)) + (bf2f(v6.z) + bf2f(v7.z)));
        a5 += ((bf2f(v0.z >> 16) + bf2f(v1.z >> 16)) + (bf2f(v2.z >> 16) + bf2f(v3.z >> 16)))
            + ((bf2f(v4.z >> 16) + bf2f(v5.z >> 16)) + (bf2f(v6.z >> 16) + bf2f(v7.z >> 16)));
        a6 += ((bf2f(v0.w) + bf2f(v1.w)) + (bf2f(v2.w) + bf2f(v3.w)))
            + ((bf2f(v4.w) + bf2f(v5.w)) + (bf2f(v6.w) + bf2f(v7.w)));
        a7 += ((bf2f(v0.w >> 16) + bf2f(v1.w >> 16)) + (bf2f(v2.w >> 16) + bf2f(v3.w >> 16)))
            + ((bf2f(v4.w >> 16) + bf2f(v5.w >> 16)) + (bf2f(v6.w >> 16) + bf2f(v7.w >> 16)));
    }
    for (; j < end; ++j) {
        const uint4 v = *(const uint4*)(xb + (size_t)csr[j] * IN_SIZE);
        a0 += bf2f(v.x); a1 += bf2f(v.x >> 16);
        a2 += bf2f(v.y); a3 += bf2f(v.y >> 16);
        a4 += bf2f(v.z); a5 += bf2f(v.z >> 16);
        a6 += bf2f(v.w); a7 += bf2f(v.w >> 16);
    }
    const float inv = 1.0f / fmaxf((float)(end - beg), 1.0f);
    uint4 o;
    o.x = (unsigned)f2bf(a0 * inv) | ((unsigned)f2bf(a1 * inv) << 16);
    o.y = (unsigned)f2bf(a2 * inv) | ((unsigned)f2bf(a3 * inv) << 16);
    o.z = (unsigned)f2bf(a4 * inv) | ((unsigned)f2bf(a5 * inv) << 16);
    o.w = (unsigned)f2bf(a6 * inv) | ((unsigned)f2bf(a7 * inv) << 16);
    *(uint4*)(msg + (size_t)d * IN_SIZE + ql * 8) = o;
}

// ---------------- layer-1 MFMA GEMM ----------------
__global__ __launch_bounds__(256) void k_gemm1(
    const unsigned short* __restrict__ A1,  // xbf [M][128]
    const unsigned short* __restrict__ A2,  // msg1 [M][128]
    const unsigned short* __restrict__ Wp,
    const float* __restrict__ bias,
    unsigned short* __restrict__ out)       // h bf16 [M][256]
{
    constexpr int NKS = 8;
    const int tid = threadIdx.x;
    const int wid = tid >> 6;
    const int lane = tid & 63;
    const int g = lane >> 4, r16 = lane & 15;
    const int i0 = blockIdx.x * 32;
    const int c0 = wid * 64;

    f32x4 acc[2][4];
    #pragma unroll
    for (int rb = 0; rb < 2; ++rb)
        #pragma unroll
        for (int cf = 0; cf < 4; ++cf)
            acc[rb][cf] = (f32x4){0.f, 0.f, 0.f, 0.f};

    #pragma unroll
    for (int ks = 0; ks < NKS; ++ks) {
        short8 a[2];
        #pragma unroll
        for (int rb = 0; rb < 2; ++rb) {
            const int row = i0 + rb * 16 + r16;
            const int kk = ks * 32 + g * 8;
            a[rb] = (ks < NKS / 2)
                ? *(const short8*)(A1 + (size_t)row * IN_SIZE + kk)
                : *(const short8*)(A2 + (size_t)row * IN_SIZE + (kk - IN_SIZE));
        }
        short8 b[4];
        #pragma unroll
        for (int cf = 0; cf < 4; ++cf) {
            const int col = c0 + cf * 16 + r16;
            b[cf] = *(const short8*)(Wp + ((size_t)ks * 256 + col) * 32 + g * 8);
        }
        #pragma unroll
        for (int rb = 0; rb < 2; ++rb)
            #pragma unroll
            for (int cf = 0; cf < 4; ++cf)
                acc[rb][cf] = __builtin_amdgcn_mfma_f32_16x16x32_bf16(
                    a[rb], b[cf], acc[rb][cf], 0, 0, 0);
    }

    #pragma unroll
    for (int cf = 0; cf < 4; ++cf) {
        const int col = c0 + cf * 16 + r16;
        const float bv = bias[col];
        #pragma unroll
        for (int rb = 0; rb < 2; ++rb)
            #pragma unroll
            for (int rr = 0; rr < 4; ++rr) {
                const int row = i0 + rb * 16 + g * 4 + rr;
                out[(size_t)row * HID + col] = f2bf(fmaxf(acc[rb][cf][rr] + bv, 0.0f));
            }
    }
}

// ---------------- layer-2 fused pull + MFMA GEMM ----------------
__global__ __launch_bounds__(256) void k_sage2(
    const unsigned short* __restrict__ h,   // [N_DST1][256] bf16
    const int* __restrict__ rp, const int* __restrict__ csr,
    const unsigned short* __restrict__ Wp,
    const float* __restrict__ bias,
    float* __restrict__ out)                // [N_DST2][256] f32
{
    __shared__ __align__(16) unsigned short At[32][264];
    const int tid = threadIdx.x;
    const int wid = tid >> 6;
    const int lane = tid & 63;
    const int i0 = blockIdx.x * 32;

    for (int r = 0; r < 8; ++r) {
        const int row = wid * 8 + r;
        const int d = i0 + row;
        const int beg = rp[d], end = rp[d + 1];
        float a0 = 0.f, a1 = 0.f, a2 = 0.f, a3 = 0.f;
        const unsigned short* hb = h + lane * 4;
        int j = beg;
        for (; j + 3 < end; j += 4) {
            const uint2 va = *(const uint2*)(hb + (size_t)csr[j + 0] * HID);
            const uint2 vb = *(const uint2*)(hb + (size_t)csr[j + 1] * HID);
            const uint2 vc = *(const uint2*)(hb + (size_t)csr[j + 2] * HID);
            const uint2 vd = *(const uint2*)(hb + (size_t)csr[j + 3] * HID);
            a0 += (bf2f(va.x) + bf2f(vb.x)) + (bf2f(vc.x) + bf2f(vd.x));
            a1 += (bf2f(va.x >> 16) + bf2f(vb.x >> 16)) + (bf2f(vc.x >> 16) + bf2f(vd.x >> 16));
            a2 += (bf2f(va.y) + bf2f(vb.y)) + (bf2f(vc.y) + bf2f(vd.y));
            a3 += (bf2f(va.y >> 16) + bf2f(vb.y >> 16)) + (bf2f(vc.y >> 16) + bf2f(vd.y >> 16));
        }
        for (; j < end; ++j) {
            const uint2 va = *(const uint2*)(hb + (size_t)csr[j] * HID);
            a0 += bf2f(va.x); a1 += bf2f(va.x >> 16);
            a2 += bf2f(va.y); a3 += bf2f(va.y >> 16);
        }
        const float inv = 1.0f / fmaxf((float)(end - beg), 1.0f);
        uint2 o;
        o.x = (unsigned)f2bf(a0 * inv) | ((unsigned)f2bf(a1 * inv) << 16);
        o.y = (unsigned)f2bf(a2 * inv) | ((unsigned)f2bf(a3 * inv) << 16);
        *(uint2*)&At[row][lane * 4] = o;
    }
    __syncthreads();

    const int g = lane >> 4, r16 = lane & 15;
    const int c0 = wid * 64;
    f32x4 acc[2][4];
    #pragma unroll
    for (int rb = 0; rb < 2; ++rb)
        #pragma unroll
        for (int cf = 0; cf < 4; ++cf)
            acc[rb][cf] = (f32x4){0.f, 0.f, 0.f, 0.f};

    #pragma unroll
    for (int ks = 0; ks < 16; ++ks) {
        short8 a[2];
        #pragma unroll
        for (int rb = 0; rb < 2; ++rb) {
            const int row16 = rb * 16 + r16;
            if (ks < 8)
                a[rb] = *(const short8*)(h + (size_t)(i0 + row16) * HID + ks * 32 + g * 8);
            else
                a[rb] = *(const short8*)&At[row16][(ks - 8) * 32 + g * 8];
        }
        short8 b[4];
        #pragma unroll
        for (int cf = 0; cf < 4; ++cf) {
            const int col = c0 + cf * 16 + r16;
            b[cf] = *(const short8*)(Wp + ((size_t)ks * 256 + col) * 32 + g * 8);
        }
        #pragma unroll
        for (int rb = 0; rb < 2; ++rb)
            #pragma unroll
            for (int cf = 0; cf < 4; ++cf)
                acc[rb][cf] = __builtin_amdgcn_mfma_f32_16x16x32_bf16(
                    a[rb], b[cf], acc[rb][cf], 0, 0, 0);
    }

    #pragma unroll
    for (int cf = 0; cf < 4; ++cf) {
        const int col = c0 + cf * 16 + r16;
        const float bv = bias[col];
        #pragma unroll
        for (int rb = 0; rb < 2; ++rb)
            #pragma unroll
            for (int rr = 0; rr < 4; ++rr) {
                const int row = i0 + rb * 16 + g * 4 + rr;
                out[(size_t)row * HID + col] = acc[rb][cf][rr] + bv;
            }
    }
}

extern "C" void kernel_launch(void* const* d_in, const int* in_sizes, int n_in,
                              void* d_out, int out_size, void* d_ws, size_t ws_size,
                              hipStream_t stream) {
    const float* x       = (const float*)d_in[0];
    const int*   src1    = (const int*)d_in[1];
    const int*   dst1    = (const int*)d_in[2];
    const int*   src2    = (const int*)d_in[3];
    const int*   dst2    = (const int*)d_in[4];
    const float* W_self1 = (const float*)d_in[5];
    const float* W_neigh1= (const float*)d_in[6];
    const float* b1      = (const float*)d_in[7];
    const float* W_self2 = (const float*)d_in[8];
    const float* W_neigh2= (const float*)d_in[9];
    const float* b2      = (const float*)d_in[10];
    float* out = (float*)d_out;

    char* ws = (char*)d_ws;
    unsigned short* xbf  = (unsigned short*)(ws + OFF_XBF);
    unsigned short* h    = (unsigned short*)(ws + OFF_H);
    unsigned short* msg1 = (unsigned short*)(ws + OFF_MSG1);
    unsigned* stg1 = (unsigned*)(ws + OFF_STG1);
    unsigned* stg2 = (unsigned*)(ws + OFF_STG2);
    int* bp1  = (int*)(ws + OFF_BP1);
    int* bp2  = (int*)(ws + OFF_BP2);
    int* bt1  = (int*)(ws + OFF_BT1);
    int* bt2  = (int*)(ws + OFF_BT2);
    int* rp1  = (int*)(ws + OFF_RP1);
    int* rp2  = (int*)(ws + OFF_RP2);
    int* csr1 = (int*)(ws + OFF_CSR1);
    int* csr2 = (int*)(ws + OFF_CSR2);
    unsigned short* wp1 = (unsigned short*)(ws + OFF_WP1);
    unsigned short* wp2 = (unsigned short*)(ws + OFF_WP2);

    k_fillA<<<P1B1 + P1B2 + 96 + CAST_A, 256, 0, stream>>>(
        x, xbf, dst1, bp1, dst2, bp2,
        W_self1, W_neigh1, wp1, W_self2, W_neigh2, wp2);
    k_fillB<<<NBIN1 + NBIN2 + CAST_B, 256, 0, stream>>>(
        bp1, bp1, bt1, bp2, bp2, bt2, x, xbf);
    k_fillC<<<P1B1 + P1B2 + CAST_C, 256, 0, stream>>>(
        src1, dst1, bp1, bt1, stg1, src2, dst2, bp2, bt2, stg2, x, xbf);
    k_fillD<<<NBIN1 + NBIN2 + CAST_D, 512, 0, stream>>>(
        stg1, bt1, rp1, csr1, stg2, bt2, rp2, csr2, x, xbf);

    k_pull1<<<N_DST1 / 16, 256, 0, stream>>>(xbf, rp1, csr1, msg1);
    k_gemm1<<<N_DST1 / 32, 256, 0, stream>>>(xbf, msg1, wp1, b1, h);
    k_sage2<<<N_DST2 / 32, 256, 0, stream>>>(h, rp2, csr2, wp2, b2, out);
}